// Round 5
// baseline (1547.488 us; speedup 1.0000x reference)
//
#include <hip/hip_runtime.h>
#include <hip/hip_bf16.h>
#include <cstdint>
#include <cstddef>

// B=4, L=2048, H=2048, NH=16, HD=128.
// Round 5 (= round 4 resubmit; broker timeout, kernel never ran):
// runtime dtype probe (cos[0]==1.0 -> u16[0]==0x3F80 iff bf16, 0x0000 iff fp32).
// All kernels branch on it; internals bf16 MFMA; output dtype follows input dtype.
// Workspace exactly 128 MB. Flash has no inf arithmetic (sentinel -1e30).

typedef __attribute__((ext_vector_type(4))) float f32x4;
typedef __attribute__((ext_vector_type(8))) short bf16x8;
typedef __attribute__((ext_vector_type(4))) unsigned short u16x4;
typedef __hip_bfloat16 bf16;

#define ASYNC16(lds, g)                                                                  \
  __builtin_amdgcn_global_load_lds((const __attribute__((address_space(1))) void*)(g),   \
                                   (__attribute__((address_space(3))) void*)(lds), 16, 0, 0)

__device__ __forceinline__ float b2f(bf16 v) { return __bfloat162float(v); }
__device__ __forceinline__ bf16 f2b(float v) { return __float2bfloat16(v); }
__device__ __forceinline__ float bs2f(unsigned short s) {
  unsigned int u = ((unsigned int)s) << 16;
  return __builtin_bit_cast(float, u);
}
__device__ __forceinline__ short f2bs(float f) {
  bf16 h = __float2bfloat16(f);
  return __builtin_bit_cast(short, h);
}
__device__ __forceinline__ bf16x8 pack8(f32x4 a, f32x4 b) {
  bf16x8 r;
#pragma unroll
  for (int t = 0; t < 4; ++t) r[t] = f2bs(a[t]);
#pragma unroll
  for (int t = 0; t < 4; ++t) r[4 + t] = f2bs(b[t]);
  return r;
}
__device__ __forceinline__ bool probe_bf16(const unsigned short* tagp) {
  return tagp[0] == 0x3F80u;
}

// ---------------------------------------------------------------------------
// Transpose+convert (R x C) -> bf16 (C x R); src fp32 or bf16 per probe.
__global__ void transpose_conv(const void* __restrict__ src, bf16* __restrict__ dst,
                               int R, int C, const unsigned short* __restrict__ tagp) {
  __shared__ float tile[32][33];
  bool bf = probe_bf16(tagp);
  int bx = blockIdx.x * 32, by = blockIdx.y * 32;
  int tx = threadIdx.x, ty = threadIdx.y;
  if (bf) {
    const bf16* s = (const bf16*)src;
    for (int i = ty; i < 32; i += 8) tile[i][tx] = b2f(s[(size_t)(by + i) * C + bx + tx]);
  } else {
    const float* s = (const float*)src;
    for (int i = ty; i < 32; i += 8) tile[i][tx] = s[(size_t)(by + i) * C + bx + tx];
  }
  __syncthreads();
  for (int i = ty; i < 32; i += 8) dst[(size_t)(bx + i) * R + by + tx] = f2b(tile[tx][i]);
}

// Bias convert -> fp32 workspace.
__global__ void conv_bias(const void* __restrict__ src, float* __restrict__ dst, int n,
                          const unsigned short* __restrict__ tagp) {
  int i = blockIdx.x * 256 + threadIdx.x;
  if (i >= n) return;
  bool bf = probe_bf16(tagp);
  dst[i] = bf ? b2f(((const bf16*)src)[i]) : ((const float*)src)[i];
}

// ---------------------------------------------------------------------------
// QKV GEMM: C(8192,6144) = x(8192,2048) * WqkvT(6144,2048)^T. 128x128 tile, BK=64.
// A staged as fp32 in LDS (works for both input dtypes), packed to bf16 at fragment load.
// B (WqkvT, ws bf16) staged via ASYNC16. Epilogue scatters Q/K/V to head layout.
__global__ __launch_bounds__(256) void gemm_qkv(const void* __restrict__ Ax,
                                                const bf16* __restrict__ Bt,
                                                const float* __restrict__ biasf,
                                                bf16* __restrict__ Qg, bf16* __restrict__ Kg,
                                                bf16* __restrict__ Vg,
                                                const unsigned short* __restrict__ tagp) {
  __shared__ alignas(16) float As[128 * 64];  // 32 KB
  __shared__ alignas(16) bf16 Bs[128 * 64];   // 16 KB
  const int K_ = 2048;
  bool bf = probe_bf16(tagp);
  int tid = threadIdx.x, lane = tid & 63, w = tid >> 6;
  int lr = lane & 15, hi = lane >> 4;
  int wm = (w >> 1) * 64, wn = (w & 1) * 64;
  int m0 = blockIdx.y * 128, n0 = blockIdx.x * 128;
  f32x4 acc[4][4];
#pragma unroll
  for (int im = 0; im < 4; ++im)
#pragma unroll
    for (int in = 0; in < 4; ++in) acc[im][in] = (f32x4){0.f, 0.f, 0.f, 0.f};

  for (int k0 = 0; k0 < K_; k0 += 64) {
    __syncthreads();
    // A: 2048 chunks of 4 floats (16B). chunk c: row r=c>>4, float-chunk j=c&15.
    if (bf) {
      const bf16* xb = (const bf16*)Ax;
#pragma unroll
      for (int i = 0; i < 8; ++i) {
        int c = tid + 256 * i;
        int r = c >> 4, j = c & 15;
        u16x4 v = *(const u16x4*)(xb + (size_t)(m0 + r) * K_ + k0 + j * 4);
        f32x4 f;
#pragma unroll
        for (int t = 0; t < 4; ++t) f[t] = bs2f(v[t]);
        *(f32x4*)(As + r * 64 + j * 4) = f;
      }
    } else {
      const float* xf = (const float*)Ax;
#pragma unroll
      for (int i = 0; i < 8; ++i) {
        int c = tid + 256 * i;
        int r = c >> 4, j = c & 15;
        ASYNC16((char*)As + c * 16, (const char*)(xf + (size_t)(m0 + r) * K_ + k0 + j * 4));
      }
    }
    // B: 1024 chunks of 8 bf16 (16B).
#pragma unroll
    for (int i = 0; i < 4; ++i) {
      int c = tid + 256 * i;
      int r = c >> 3, j = c & 7;
      ASYNC16((char*)Bs + c * 16, (const char*)(Bt + (size_t)(n0 + r) * K_ + k0 + j * 8));
    }
    __syncthreads();

#pragma unroll
    for (int ks = 0; ks < 2; ++ks) {
      bf16x8 afr[4], bfr[4];
#pragma unroll
      for (int im = 0; im < 4; ++im) {
        int r = wm + 16 * im + lr;
        const float* ap = As + r * 64 + (ks * 4 + hi) * 8;
        f32x4 a0 = *(const f32x4*)ap;
        f32x4 a1 = *(const f32x4*)(ap + 4);
        afr[im] = pack8(a0, a1);
      }
#pragma unroll
      for (int in = 0; in < 4; ++in) {
        int r = wn + 16 * in + lr;
        bfr[in] = *(const bf16x8*)((const char*)Bs + r * 128 + (ks * 4 + hi) * 16);
      }
#pragma unroll
      for (int im = 0; im < 4; ++im)
#pragma unroll
        for (int in = 0; in < 4; ++in)
          acc[im][in] =
              __builtin_amdgcn_mfma_f32_16x16x32_bf16(afr[im], bfr[in], acc[im][in], 0, 0, 0);
    }
  }

  // Epilogue: col c -> which=c>>11; of cc=c&2047: h=cc&15, d=cc>>4.
#pragma unroll
  for (int im = 0; im < 4; ++im) {
    int mrow = m0 + wm + 16 * im + 4 * hi;
#pragma unroll
    for (int in = 0; in < 4; ++in) {
      int c = n0 + wn + 16 * in + lr;
      int which = c >> 11, cc = c & 2047;
      int hh = cc & 15, d = cc >> 4;
      float bv = biasf[c];
#pragma unroll
      for (int j = 0; j < 4; ++j) {
        int m = mrow + j;
        int bb = m >> 11, l = m & 2047;
        int bh = bb * 16 + hh;
        bf16 hv = f2b(acc[im][in][j] + bv);
        if (which == 0)
          Qg[((size_t)bh * 2048 + l) * 128 + d] = hv;
        else if (which == 1)
          Kg[((size_t)bh * 2048 + l) * 128 + d] = hv;
        else
          Vg[((size_t)bh * 128 + d) * 2048 + l] = hv;
      }
    }
  }
}

// ---------------------------------------------------------------------------
// FC2 GEMM: Out(8192,2048) = Y(8192,2048) * Wfc2T(2048,2048)^T, bias+SiLU.
// Y is ws bf16 -> pure ASYNC16 core. Output dtype follows probe.
__global__ __launch_bounds__(256) void gemm_fc2(const bf16* __restrict__ A,
                                                const bf16* __restrict__ Bt,
                                                const float* __restrict__ biasf,
                                                void* __restrict__ Out,
                                                const unsigned short* __restrict__ tagp) {
  __shared__ alignas(16) bf16 As[128 * 64];
  __shared__ alignas(16) bf16 Bs[128 * 64];
  const int K_ = 2048;
  bool obf = probe_bf16(tagp);
  int tid = threadIdx.x, lane = tid & 63, w = tid >> 6;
  int lr = lane & 15, hi = lane >> 4;
  int wm = (w >> 1) * 64, wn = (w & 1) * 64;
  int m0 = blockIdx.y * 128, n0 = blockIdx.x * 128;
  f32x4 acc[4][4];
#pragma unroll
  for (int im = 0; im < 4; ++im)
#pragma unroll
    for (int in = 0; in < 4; ++in) acc[im][in] = (f32x4){0.f, 0.f, 0.f, 0.f};

  for (int k0 = 0; k0 < K_; k0 += 64) {
    __syncthreads();
#pragma unroll
    for (int i = 0; i < 4; ++i) {
      int c = tid + 256 * i;
      int r = c >> 3, j = c & 7;
      ASYNC16((char*)As + c * 16, (const char*)(A + (size_t)(m0 + r) * K_ + k0 + j * 8));
    }
#pragma unroll
    for (int i = 0; i < 4; ++i) {
      int c = tid + 256 * i;
      int r = c >> 3, j = c & 7;
      ASYNC16((char*)Bs + c * 16, (const char*)(Bt + (size_t)(n0 + r) * K_ + k0 + j * 8));
    }
    __syncthreads();
#pragma unroll
    for (int ks = 0; ks < 2; ++ks) {
      bf16x8 afr[4], bfr[4];
#pragma unroll
      for (int im = 0; im < 4; ++im) {
        int r = wm + 16 * im + lr;
        afr[im] = *(const bf16x8*)((const char*)As + r * 128 + (ks * 4 + hi) * 16);
      }
#pragma unroll
      for (int in = 0; in < 4; ++in) {
        int r = wn + 16 * in + lr;
        bfr[in] = *(const bf16x8*)((const char*)Bs + r * 128 + (ks * 4 + hi) * 16);
      }
#pragma unroll
      for (int im = 0; im < 4; ++im)
#pragma unroll
        for (int in = 0; in < 4; ++in)
          acc[im][in] =
              __builtin_amdgcn_mfma_f32_16x16x32_bf16(afr[im], bfr[in], acc[im][in], 0, 0, 0);
    }
  }

#pragma unroll
  for (int im = 0; im < 4; ++im) {
#pragma unroll
    for (int in = 0; in < 4; ++in) {
      int c = n0 + wn + 16 * in + lr;
      float bv = biasf[c];
#pragma unroll
      for (int j = 0; j < 4; ++j) {
        int m = m0 + wm + 16 * im + 4 * hi + j;
        float z = acc[im][in][j] + bv;
        float sv = z / (1.f + __expf(-z));
        size_t off = (size_t)m * 2048 + c;
        if (obf)
          ((bf16*)Out)[off] = f2b(sv);
        else
          ((float*)Out)[off] = sv;
      }
    }
  }
}

// ---------------------------------------------------------------------------
// Rotary in-place on Q,K head layout. Pair (d, d+64), angle col = d*16+h.
__global__ void rotary_kernel(bf16* __restrict__ Qg, bf16* __restrict__ Kg,
                              const void* __restrict__ cosp, const void* __restrict__ sinp,
                              const unsigned short* __restrict__ tagp) {
  int idx = blockIdx.x * 256 + threadIdx.x;  // B*NH*L*64 = 8388608
  bool bf = probe_bf16(tagp);
  int d = idx & 63;
  int l = (idx >> 6) & 2047;
  int bh = idx >> 17;
  int h = bh & 15;
  size_t base = ((size_t)bh * 2048 + l) * 128;
  int ang = l * 1024 + d * 16 + h;
  float c, s;
  if (bf) {
    c = b2f(((const bf16*)cosp)[ang]);
    s = b2f(((const bf16*)sinp)[ang]);
  } else {
    c = ((const float*)cosp)[ang];
    s = ((const float*)sinp)[ang];
  }
  float q1 = b2f(Qg[base + d]), q2 = b2f(Qg[base + d + 64]);
  Qg[base + d] = f2b(q1 * c + q2 * s);
  Qg[base + d + 64] = f2b(-q1 * s + q2 * c);
  float k1 = b2f(Kg[base + d]), k2 = b2f(Kg[base + d + 64]);
  Kg[base + d] = f2b(k1 * c + k2 * s);
  Kg[base + d + 64] = f2b(-k1 * s + k2 * c);
}

// ---------------------------------------------------------------------------
// Causal flash attention (all-bf16 workspace operands; no inf arithmetic).
__global__ __launch_bounds__(256) void flash_kernel(const bf16* __restrict__ Qg,
                                                    const bf16* __restrict__ Kg,
                                                    const bf16* __restrict__ Vg,
                                                    bf16* __restrict__ Y) {
  __shared__ alignas(16) bf16 Qs[64 * 128];
  __shared__ alignas(16) bf16 Ks[64 * 128];
  __shared__ alignas(16) bf16 Vt[128 * 64];
  __shared__ alignas(16) bf16 Ps[4 * 16 * 72];
  int tid = threadIdx.x, lane = tid & 63, w = tid >> 6;
  int lr = lane & 15, hi = lane >> 4;
  int it = 31 - (int)blockIdx.x;
  int bh = blockIdx.y;
  int b = bh >> 4, h = bh & 15;
  int q0 = it * 64;
  const bf16* Qb = Qg + (size_t)bh * 2048 * 128;
  const bf16* Kb = Kg + (size_t)bh * 2048 * 128;
  const bf16* Vb = Vg + (size_t)bh * 128 * 2048;
  const float NEG = -1.0e30f;

#pragma unroll
  for (int i = 0; i < 4; ++i) {
    int c = tid + 256 * i;
    int r = c >> 4, j = c & 15;
    ASYNC16((char*)Qs + c * 16, (const char*)(Qb + (size_t)(q0 + r) * 128 + j * 8));
  }

  f32x4 o[8];
#pragma unroll
  for (int i = 0; i < 8; ++i) o[i] = (f32x4){0.f, 0.f, 0.f, 0.f};
  float m_i[4], l_i[4];
#pragma unroll
  for (int j = 0; j < 4; ++j) { m_i[j] = NEG; l_i[j] = 0.f; }
  const float scale = 0.08838834764831845f;  // 1/sqrt(128)

  for (int jt = 0; jt <= it; ++jt) {
    int k0 = jt * 64;
    __syncthreads();
#pragma unroll
    for (int i = 0; i < 4; ++i) {
      int c = tid + 256 * i;
      int r = c >> 4, j = c & 15;
      ASYNC16((char*)Ks + c * 16, (const char*)(Kb + (size_t)(k0 + r) * 128 + j * 8));
    }
#pragma unroll
    for (int i = 0; i < 4; ++i) {
      int c = tid + 256 * i;
      int r = c >> 3, j = c & 7;
      ASYNC16((char*)Vt + c * 16, (const char*)(Vb + (size_t)r * 2048 + k0 + j * 8));
    }
    __syncthreads();

    f32x4 sacc[4];
#pragma unroll
    for (int in = 0; in < 4; ++in) sacc[in] = (f32x4){0.f, 0.f, 0.f, 0.f};
#pragma unroll
    for (int ks = 0; ks < 4; ++ks) {
      int ar = 16 * w + lr;
      bf16x8 a = *(const bf16x8*)((const char*)Qs + ar * 256 + (ks * 4 + hi) * 16);
#pragma unroll
      for (int in = 0; in < 4; ++in) {
        int br = 16 * in + lr;
        bf16x8 bb = *(const bf16x8*)((const char*)Ks + br * 256 + (ks * 4 + hi) * 16);
        sacc[in] = __builtin_amdgcn_mfma_f32_16x16x32_bf16(a, bb, sacc[in], 0, 0, 0);
      }
    }

    bool diag = (jt == it);
#pragma unroll
    for (int j = 0; j < 4; ++j) {
      float mx = NEG;
#pragma unroll
      for (int in = 0; in < 4; ++in) {
        float s = sacc[in][j] * scale;
        if (diag) {
          int qg = 16 * w + 4 * hi + j;
          int kg = 16 * in + lr;
          if (kg > qg) s = NEG;
        }
        sacc[in][j] = s;
        mx = fmaxf(mx, s);
      }
#pragma unroll
      for (int off = 1; off < 16; off <<= 1) mx = fmaxf(mx, __shfl_xor(mx, off));
      float mnew = fmaxf(m_i[j], mx);
      float alpha = __expf(m_i[j] - mnew);
      float rs = 0.f;
#pragma unroll
      for (int in = 0; in < 4; ++in) {
        float p = __expf(sacc[in][j] - mnew);
        sacc[in][j] = p;
        rs += p;
      }
#pragma unroll
      for (int off = 1; off < 16; off <<= 1) rs += __shfl_xor(rs, off);
      l_i[j] = alpha * l_i[j] + rs;
      m_i[j] = mnew;
#pragma unroll
      for (int inp = 0; inp < 8; ++inp) o[inp][j] *= alpha;
    }

#pragma unroll
    for (int j = 0; j < 4; ++j)
#pragma unroll
      for (int in = 0; in < 4; ++in)
        Ps[w * 1152 + (4 * hi + j) * 72 + 16 * in + lr] = f2b(sacc[in][j]);
    __syncthreads();

#pragma unroll
    for (int ko = 0; ko < 2; ++ko) {
      bf16x8 a = *(const bf16x8*)((const char*)Ps + (w * 1152 + lr * 72 + ko * 32 + hi * 8) * 2);
#pragma unroll
      for (int inp = 0; inp < 8; ++inp) {
        int br = 16 * inp + lr;
        bf16x8 bb = *(const bf16x8*)((const char*)Vt + br * 128 + (ko * 4 + hi) * 16);
        o[inp] = __builtin_amdgcn_mfma_f32_16x16x32_bf16(a, bb, o[inp], 0, 0, 0);
      }
    }
  }

#pragma unroll
  for (int j = 0; j < 4; ++j) {
    int qg = q0 + 16 * w + 4 * hi + j;
    float inv = 1.f / l_i[j];
    size_t rowb = ((size_t)(b * 2048 + qg)) * 2048 + h * 128;
#pragma unroll
    for (int inp = 0; inp < 8; ++inp) {
      int dd = 16 * inp + lr;
      Y[rowb + dd] = f2b(o[inp][j] * inv);
    }
  }
}

// ---------------------------------------------------------------------------
extern "C" void kernel_launch(void* const* d_in, const int* in_sizes, int n_in,
                              void* d_out, int out_size, void* d_ws, size_t ws_size,
                              hipStream_t stream) {
  const void* x    = d_in[0];  // 8192 x 2048
  const void* Wqkv = d_in[1];  // 2048 x 6144
  const void* bqkv = d_in[2];  // 6144
  const void* Wfc2 = d_in[3];  // 2048 x 2048
  const void* bfc2 = d_in[4];  // 2048
  const void* cosp = d_in[5];  // 2048 x 1024
  const void* sinp = d_in[6];  // 2048 x 1024
  const unsigned short* tagp = (const unsigned short*)cosp;  // dtype probe

  // Workspace (bf16 elems), exactly 67,108,864 = 128 MB:
  //   [0, 16.78M):      Yg. Pre-flash aliases: WqkvT [0,12.58M), bq_f32 @14.68M (6144 fp32).
  //   [16.78M, 33.55M): Qg. Post-flash aliases: Wfc2T [+0,+4.19M), bf2_f32 @+8.39M (2048 fp32).
  //   [33.55M, 50.33M): Kg.
  //   [50.33M, 67.11M): Vg [bh][128][l].
  bf16* ws = (bf16*)d_ws;
  bf16* Yg      = ws;
  bf16* WqkvT   = ws;
  float* bq_f32 = (float*)(ws + 14680064);
  bf16* Qg      = ws + 16777216;
  bf16* Wfc2T   = ws + 16777216;
  float* bf2_f32= (float*)(ws + 16777216 + 8388608);
  bf16* Kg      = ws + 33554432;
  bf16* Vg      = ws + 50331648;

  conv_bias<<<24, 256, 0, stream>>>(bqkv, bq_f32, 6144, tagp);
  transpose_conv<<<dim3(192, 64), dim3(32, 8), 0, stream>>>(Wqkv, WqkvT, 2048, 6144, tagp);
  gemm_qkv<<<dim3(48, 64), 256, 0, stream>>>(x, WqkvT, bq_f32, Qg, Kg, Vg, tagp);
  rotary_kernel<<<32768, 256, 0, stream>>>(Qg, Kg, cosp, sinp, tagp);
  flash_kernel<<<dim3(32, 64), 256, 0, stream>>>(Qg, Kg, Vg, Yg);
  transpose_conv<<<dim3(64, 64), dim3(32, 8), 0, stream>>>(Wfc2, Wfc2T, 2048, 2048, tagp);
  conv_bias<<<8, 256, 0, stream>>>(bfc2, bf2_f32, 2048, tagp);
  gemm_fc2<<<dim3(16, 64), 256, 0, stream>>>(Yg, Wfc2T, bf2_f32, d_out, tagp);
}

// Round 6
// 1351.170 us; speedup vs baseline: 1.1453x; 1.1453x over previous
//
#include <hip/hip_runtime.h>
#include <hip/hip_bf16.h>
#include <cstdint>
#include <cstddef>

// B=4, L=2048, H=2048, NH=16, HD=128. Inputs/outputs fp32 (confirmed round 5).
// Round 6: gemm_qkv A-path converts fp32->bf16 at staging (pure bf16 inner loop);
// XOR chunk swizzle (slot = j ^ (r&7)) on As/Bs in both GEMMs -> 2-way (free) reads.
// Flash kernel untouched this round. Workspace exactly 128 MB.

typedef __attribute__((ext_vector_type(4))) float f32x4;
typedef __attribute__((ext_vector_type(8))) short bf16x8;
typedef __hip_bfloat16 bf16;

#define ASYNC16(lds, g)                                                                  \
  __builtin_amdgcn_global_load_lds((const __attribute__((address_space(1))) void*)(g),   \
                                   (__attribute__((address_space(3))) void*)(lds), 16, 0, 0)

__device__ __forceinline__ float b2f(bf16 v) { return __bfloat162float(v); }
__device__ __forceinline__ bf16 f2b(float v) { return __float2bfloat16(v); }
__device__ __forceinline__ short f2bs(float f) {
  bf16 h = __float2bfloat16(f);
  return __builtin_bit_cast(short, h);
}
__device__ __forceinline__ bf16x8 pack8(f32x4 a, f32x4 b) {
  bf16x8 r;
#pragma unroll
  for (int t = 0; t < 4; ++t) r[t] = f2bs(a[t]);
#pragma unroll
  for (int t = 0; t < 4; ++t) r[4 + t] = f2bs(b[t]);
  return r;
}

// ---------------------------------------------------------------------------
// Transpose+convert fp32 (R x C) -> bf16 (C x R).
__global__ void transpose_conv(const float* __restrict__ src, bf16* __restrict__ dst,
                               int R, int C) {
  __shared__ float tile[32][33];
  int bx = blockIdx.x * 32, by = blockIdx.y * 32;
  int tx = threadIdx.x, ty = threadIdx.y;
  for (int i = ty; i < 32; i += 8) tile[i][tx] = src[(size_t)(by + i) * C + bx + tx];
  __syncthreads();
  for (int i = ty; i < 32; i += 8) dst[(size_t)(bx + i) * R + by + tx] = f2b(tile[tx][i]);
}

// ---------------------------------------------------------------------------
// QKV GEMM: C(8192,6144) = x(8192,2048) * WqkvT(6144,2048)^T. 128x128 tile, BK=64.
// A: global fp32 -> VGPR -> pack bf16 -> ds_write_b128 (swizzled slot).
// B: ASYNC16 with swizzled GLOBAL source chunk. Reads use slot (q ^ (r&7)).
__global__ __launch_bounds__(256) void gemm_qkv(const float* __restrict__ Ax,
                                                const bf16* __restrict__ Bt,
                                                const float* __restrict__ biasf,
                                                bf16* __restrict__ Qg, bf16* __restrict__ Kg,
                                                bf16* __restrict__ Vg) {
  __shared__ alignas(16) bf16 As[128 * 64];  // 16 KB
  __shared__ alignas(16) bf16 Bs[128 * 64];  // 16 KB
  const int K_ = 2048;
  int tid = threadIdx.x, lane = tid & 63, w = tid >> 6;
  int lr = lane & 15, hi = lane >> 4;
  int wm = (w >> 1) * 64, wn = (w & 1) * 64;
  int m0 = blockIdx.y * 128, n0 = blockIdx.x * 128;
  f32x4 acc[4][4];
#pragma unroll
  for (int im = 0; im < 4; ++im)
#pragma unroll
    for (int in = 0; in < 4; ++in) acc[im][in] = (f32x4){0.f, 0.f, 0.f, 0.f};

  for (int k0 = 0; k0 < K_; k0 += 64) {
    __syncthreads();
    // A: 1024 bf16-chunks (16B = 8 elems). chunk c: row r=c>>3, chunk j=c&7.
#pragma unroll
    for (int i = 0; i < 4; ++i) {
      int c = tid + 256 * i;
      int r = c >> 3, j = c & 7;
      const float* gp = Ax + (size_t)(m0 + r) * K_ + k0 + j * 8;
      f32x4 a0 = *(const f32x4*)gp;
      f32x4 a1 = *(const f32x4*)(gp + 4);
      *(bf16x8*)((char*)As + r * 128 + ((j ^ (r & 7)) * 16)) = pack8(a0, a1);
    }
    // B: ASYNC16, swizzle applied to the global source chunk index.
#pragma unroll
    for (int i = 0; i < 4; ++i) {
      int c = tid + 256 * i;
      int r = c >> 3, j = c & 7, jg = j ^ (r & 7);
      ASYNC16((char*)Bs + c * 16, (const char*)(Bt + (size_t)(n0 + r) * K_ + k0 + jg * 8));
    }
    __syncthreads();

#pragma unroll
    for (int ks = 0; ks < 2; ++ks) {
      bf16x8 afr[4], bfr[4];
#pragma unroll
      for (int im = 0; im < 4; ++im) {
        int r = wm + 16 * im + lr;
        afr[im] = *(const bf16x8*)((const char*)As + r * 128 + (((ks * 4 + hi) ^ (r & 7)) * 16));
      }
#pragma unroll
      for (int in = 0; in < 4; ++in) {
        int r = wn + 16 * in + lr;
        bfr[in] = *(const bf16x8*)((const char*)Bs + r * 128 + (((ks * 4 + hi) ^ (r & 7)) * 16));
      }
#pragma unroll
      for (int im = 0; im < 4; ++im)
#pragma unroll
        for (int in = 0; in < 4; ++in)
          acc[im][in] =
              __builtin_amdgcn_mfma_f32_16x16x32_bf16(afr[im], bfr[in], acc[im][in], 0, 0, 0);
    }
  }

  // Epilogue: col c -> which=c>>11; of cc=c&2047: h=cc&15, d=cc>>4.
#pragma unroll
  for (int im = 0; im < 4; ++im) {
    int mrow = m0 + wm + 16 * im + 4 * hi;
#pragma unroll
    for (int in = 0; in < 4; ++in) {
      int c = n0 + wn + 16 * in + lr;
      int which = c >> 11, cc = c & 2047;
      int hh = cc & 15, d = cc >> 4;
      float bv = biasf[c];
#pragma unroll
      for (int j = 0; j < 4; ++j) {
        int m = mrow + j;
        int bb = m >> 11, l = m & 2047;
        int bh = bb * 16 + hh;
        bf16 hv = f2b(acc[im][in][j] + bv);
        if (which == 0)
          Qg[((size_t)bh * 2048 + l) * 128 + d] = hv;
        else if (which == 1)
          Kg[((size_t)bh * 2048 + l) * 128 + d] = hv;
        else
          Vg[((size_t)bh * 128 + d) * 2048 + l] = hv;
      }
    }
  }
}

// ---------------------------------------------------------------------------
// FC2 GEMM: Out(8192,2048) = Y(8192,2048) * Wfc2T(2048,2048)^T, bias+SiLU, fp32 out.
// Both operands bf16 in ws -> ASYNC16 with swizzled source; swizzled reads.
__global__ __launch_bounds__(256) void gemm_fc2(const bf16* __restrict__ A,
                                                const bf16* __restrict__ Bt,
                                                const float* __restrict__ biasf,
                                                float* __restrict__ Out) {
  __shared__ alignas(16) bf16 As[128 * 64];
  __shared__ alignas(16) bf16 Bs[128 * 64];
  const int K_ = 2048;
  int tid = threadIdx.x, lane = tid & 63, w = tid >> 6;
  int lr = lane & 15, hi = lane >> 4;
  int wm = (w >> 1) * 64, wn = (w & 1) * 64;
  int m0 = blockIdx.y * 128, n0 = blockIdx.x * 128;
  f32x4 acc[4][4];
#pragma unroll
  for (int im = 0; im < 4; ++im)
#pragma unroll
    for (int in = 0; in < 4; ++in) acc[im][in] = (f32x4){0.f, 0.f, 0.f, 0.f};

  for (int k0 = 0; k0 < K_; k0 += 64) {
    __syncthreads();
#pragma unroll
    for (int i = 0; i < 4; ++i) {
      int c = tid + 256 * i;
      int r = c >> 3, j = c & 7, jg = j ^ (r & 7);
      ASYNC16((char*)As + c * 16, (const char*)(A + (size_t)(m0 + r) * K_ + k0 + jg * 8));
    }
#pragma unroll
    for (int i = 0; i < 4; ++i) {
      int c = tid + 256 * i;
      int r = c >> 3, j = c & 7, jg = j ^ (r & 7);
      ASYNC16((char*)Bs + c * 16, (const char*)(Bt + (size_t)(n0 + r) * K_ + k0 + jg * 8));
    }
    __syncthreads();
#pragma unroll
    for (int ks = 0; ks < 2; ++ks) {
      bf16x8 afr[4], bfr[4];
#pragma unroll
      for (int im = 0; im < 4; ++im) {
        int r = wm + 16 * im + lr;
        afr[im] = *(const bf16x8*)((const char*)As + r * 128 + (((ks * 4 + hi) ^ (r & 7)) * 16));
      }
#pragma unroll
      for (int in = 0; in < 4; ++in) {
        int r = wn + 16 * in + lr;
        bfr[in] = *(const bf16x8*)((const char*)Bs + r * 128 + (((ks * 4 + hi) ^ (r & 7)) * 16));
      }
#pragma unroll
      for (int im = 0; im < 4; ++im)
#pragma unroll
        for (int in = 0; in < 4; ++in)
          acc[im][in] =
              __builtin_amdgcn_mfma_f32_16x16x32_bf16(afr[im], bfr[in], acc[im][in], 0, 0, 0);
    }
  }

#pragma unroll
  for (int im = 0; im < 4; ++im) {
#pragma unroll
    for (int in = 0; in < 4; ++in) {
      int c = n0 + wn + 16 * in + lr;
      float bv = biasf[c];
#pragma unroll
      for (int j = 0; j < 4; ++j) {
        int m = m0 + wm + 16 * im + 4 * hi + j;
        float z = acc[im][in][j] + bv;
        Out[(size_t)m * 2048 + c] = z / (1.f + __expf(-z));
      }
    }
  }
}

// ---------------------------------------------------------------------------
// Rotary in-place on Q,K head layout. Pair (d, d+64), angle col = d*16+h. fp32 cos/sin.
__global__ void rotary_kernel(bf16* __restrict__ Qg, bf16* __restrict__ Kg,
                              const float* __restrict__ cosp, const float* __restrict__ sinp) {
  int idx = blockIdx.x * 256 + threadIdx.x;  // B*NH*L*64 = 8388608
  int d = idx & 63;
  int l = (idx >> 6) & 2047;
  int bh = idx >> 17;
  int h = bh & 15;
  size_t base = ((size_t)bh * 2048 + l) * 128;
  int ang = l * 1024 + d * 16 + h;
  float c = cosp[ang], s = sinp[ang];
  float q1 = b2f(Qg[base + d]), q2 = b2f(Qg[base + d + 64]);
  Qg[base + d] = f2b(q1 * c + q2 * s);
  Qg[base + d + 64] = f2b(-q1 * s + q2 * c);
  float k1 = b2f(Kg[base + d]), k2 = b2f(Kg[base + d + 64]);
  Kg[base + d] = f2b(k1 * c + k2 * s);
  Kg[base + d + 64] = f2b(-k1 * s + k2 * c);
}

// ---------------------------------------------------------------------------
// Causal flash attention (unchanged from round 5; counters next round).
__global__ __launch_bounds__(256) void flash_kernel(const bf16* __restrict__ Qg,
                                                    const bf16* __restrict__ Kg,
                                                    const bf16* __restrict__ Vg,
                                                    bf16* __restrict__ Y) {
  __shared__ alignas(16) bf16 Qs[64 * 128];
  __shared__ alignas(16) bf16 Ks[64 * 128];
  __shared__ alignas(16) bf16 Vt[128 * 64];
  __shared__ alignas(16) bf16 Ps[4 * 16 * 72];
  int tid = threadIdx.x, lane = tid & 63, w = tid >> 6;
  int lr = lane & 15, hi = lane >> 4;
  int it = 31 - (int)blockIdx.x;
  int bh = blockIdx.y;
  int b = bh >> 4, h = bh & 15;
  int q0 = it * 64;
  const bf16* Qb = Qg + (size_t)bh * 2048 * 128;
  const bf16* Kb = Kg + (size_t)bh * 2048 * 128;
  const bf16* Vb = Vg + (size_t)bh * 128 * 2048;
  const float NEG = -1.0e30f;

#pragma unroll
  for (int i = 0; i < 4; ++i) {
    int c = tid + 256 * i;
    int r = c >> 4, j = c & 15;
    ASYNC16((char*)Qs + c * 16, (const char*)(Qb + (size_t)(q0 + r) * 128 + j * 8));
  }

  f32x4 o[8];
#pragma unroll
  for (int i = 0; i < 8; ++i) o[i] = (f32x4){0.f, 0.f, 0.f, 0.f};
  float m_i[4], l_i[4];
#pragma unroll
  for (int j = 0; j < 4; ++j) { m_i[j] = NEG; l_i[j] = 0.f; }
  const float scale = 0.08838834764831845f;  // 1/sqrt(128)

  for (int jt = 0; jt <= it; ++jt) {
    int k0 = jt * 64;
    __syncthreads();
#pragma unroll
    for (int i = 0; i < 4; ++i) {
      int c = tid + 256 * i;
      int r = c >> 4, j = c & 15;
      ASYNC16((char*)Ks + c * 16, (const char*)(Kb + (size_t)(k0 + r) * 128 + j * 8));
    }
#pragma unroll
    for (int i = 0; i < 4; ++i) {
      int c = tid + 256 * i;
      int r = c >> 3, j = c & 7;
      ASYNC16((char*)Vt + c * 16, (const char*)(Vb + (size_t)r * 2048 + k0 + j * 8));
    }
    __syncthreads();

    f32x4 sacc[4];
#pragma unroll
    for (int in = 0; in < 4; ++in) sacc[in] = (f32x4){0.f, 0.f, 0.f, 0.f};
#pragma unroll
    for (int ks = 0; ks < 4; ++ks) {
      int ar = 16 * w + lr;
      bf16x8 a = *(const bf16x8*)((const char*)Qs + ar * 256 + (ks * 4 + hi) * 16);
#pragma unroll
      for (int in = 0; in < 4; ++in) {
        int br = 16 * in + lr;
        bf16x8 bb = *(const bf16x8*)((const char*)Ks + br * 256 + (ks * 4 + hi) * 16);
        sacc[in] = __builtin_amdgcn_mfma_f32_16x16x32_bf16(a, bb, sacc[in], 0, 0, 0);
      }
    }

    bool diag = (jt == it);
#pragma unroll
    for (int j = 0; j < 4; ++j) {
      float mx = NEG;
#pragma unroll
      for (int in = 0; in < 4; ++in) {
        float s = sacc[in][j] * scale;
        if (diag) {
          int qg = 16 * w + 4 * hi + j;
          int kg = 16 * in + lr;
          if (kg > qg) s = NEG;
        }
        sacc[in][j] = s;
        mx = fmaxf(mx, s);
      }
#pragma unroll
      for (int off = 1; off < 16; off <<= 1) mx = fmaxf(mx, __shfl_xor(mx, off));
      float mnew = fmaxf(m_i[j], mx);
      float alpha = __expf(m_i[j] - mnew);
      float rs = 0.f;
#pragma unroll
      for (int in = 0; in < 4; ++in) {
        float p = __expf(sacc[in][j] - mnew);
        sacc[in][j] = p;
        rs += p;
      }
#pragma unroll
      for (int off = 1; off < 16; off <<= 1) rs += __shfl_xor(rs, off);
      l_i[j] = alpha * l_i[j] + rs;
      m_i[j] = mnew;
#pragma unroll
      for (int inp = 0; inp < 8; ++inp) o[inp][j] *= alpha;
    }

#pragma unroll
    for (int j = 0; j < 4; ++j)
#pragma unroll
      for (int in = 0; in < 4; ++in)
        Ps[w * 1152 + (4 * hi + j) * 72 + 16 * in + lr] = f2b(sacc[in][j]);
    __syncthreads();

#pragma unroll
    for (int ko = 0; ko < 2; ++ko) {
      bf16x8 a = *(const bf16x8*)((const char*)Ps + (w * 1152 + lr * 72 + ko * 32 + hi * 8) * 2);
#pragma unroll
      for (int inp = 0; inp < 8; ++inp) {
        int br = 16 * inp + lr;
        bf16x8 bb = *(const bf16x8*)((const char*)Vt + br * 128 + (ko * 4 + hi) * 16);
        o[inp] = __builtin_amdgcn_mfma_f32_16x16x32_bf16(a, bb, o[inp], 0, 0, 0);
      }
    }
  }

#pragma unroll
  for (int j = 0; j < 4; ++j) {
    int qg = q0 + 16 * w + 4 * hi + j;
    float inv = 1.f / l_i[j];
    size_t rowb = ((size_t)(b * 2048 + qg)) * 2048 + h * 128;
#pragma unroll
    for (int inp = 0; inp < 8; ++inp) {
      int dd = 16 * inp + lr;
      Y[rowb + dd] = f2b(o[inp][j] * inv);
    }
  }
}

// ---------------------------------------------------------------------------
extern "C" void kernel_launch(void* const* d_in, const int* in_sizes, int n_in,
                              void* d_out, int out_size, void* d_ws, size_t ws_size,
                              hipStream_t stream) {
  const float* x    = (const float*)d_in[0];  // 8192 x 2048
  const float* Wqkv = (const float*)d_in[1];  // 2048 x 6144
  const float* bqkv = (const float*)d_in[2];  // 6144
  const float* Wfc2 = (const float*)d_in[3];  // 2048 x 2048
  const float* bfc2 = (const float*)d_in[4];  // 2048
  const float* cosp = (const float*)d_in[5];  // 2048 x 1024
  const float* sinp = (const float*)d_in[6];  // 2048 x 1024
  float* out = (float*)d_out;

  // Workspace (bf16 elems), exactly 67,108,864 = 128 MB:
  //   [0, 16.78M):      Yg (flash out). WqkvT [0,12.58M) aliased pre-flash.
  //   [16.78M, 33.55M): Qg. Wfc2T [+0,+4.19M) aliased post-flash.
  //   [33.55M, 50.33M): Kg.
  //   [50.33M, 67.11M): Vg [bh][128][l].
  bf16* ws = (bf16*)d_ws;
  bf16* Yg    = ws;
  bf16* WqkvT = ws;
  bf16* Qg    = ws + 16777216;
  bf16* Wfc2T = ws + 16777216;
  bf16* Kg    = ws + 33554432;
  bf16* Vg    = ws + 50331648;

  transpose_conv<<<dim3(192, 64), dim3(32, 8), 0, stream>>>(Wqkv, WqkvT, 2048, 6144);
  gemm_qkv<<<dim3(48, 64), 256, 0, stream>>>(x, WqkvT, bqkv, Qg, Kg, Vg);
  rotary_kernel<<<32768, 256, 0, stream>>>(Qg, Kg, cosp, sinp);
  flash_kernel<<<dim3(32, 64), 256, 0, stream>>>(Qg, Kg, Vg, Yg);
  transpose_conv<<<dim3(64, 64), dim3(32, 8), 0, stream>>>(Wfc2, Wfc2T, 2048, 2048);
  gemm_fc2<<<dim3(16, 64), 256, 0, stream>>>(Yg, Wfc2T, bfc2, out);
}